// Round 11
// baseline (260.500 us; speedup 1.0000x reference)
//
#include <hip/hip_runtime.h>

typedef _Float16 f16;
typedef _Float16 f16x2 __attribute__((ext_vector_type(2)));
typedef _Float16 f16x4 __attribute__((ext_vector_type(4)));
typedef unsigned int u32x4 __attribute__((ext_vector_type(4)));

#define VOCAB 100000
#define DIM 128
#define BATCH 262144
#define NEG 5

#define NBLOCK 2048
#define NTHREADS 256
#define NGRP8 (NBLOCK * NTHREADS / 8)      // 65536 8-lane groups
#define EPG8 (BATCH / NGRP8)               // 4 elements per group, exact

#define TABLE_HALF_BYTES ((size_t)VOCAB * DIM * 2)            // 25.6 MB
#define WS_NEEDED (256 + 2 * TABLE_HALF_BYTES)

// log(1 + exp(x)); |x| <~ 0.04 here so exp(-|x|) ~ 1: no cancellation risk.
__device__ __forceinline__ float softplus_fast(float x) {
    return fmaxf(x, 0.0f) + __logf(1.0f + __expf(-fabsf(x)));
}

__device__ __forceinline__ float fdot2h(f16x2 a, f16x2 b, float c) {
#if __has_builtin(__builtin_amdgcn_fdot2)
    return __builtin_amdgcn_fdot2(a, b, c, false);
#else
    return c + (float)a[0] * (float)b[0] + (float)a[1] * (float)b[1];
#endif
}

// dot of 8 halves per operand pair, fp32 accumulate
__device__ __forceinline__ float dot8h(u32x4 a, u32x4 b) {
    union { u32x4 u; f16x2 h[4]; } A, B;
    A.u = a; B.u = b;
    float s0 = fdot2h(A.h[0], B.h[0], 0.0f);
    float s1 = fdot2h(A.h[1], B.h[1], 0.0f);
    s0 = fdot2h(A.h[2], B.h[2], s0);
    s1 = fdot2h(A.h[3], B.h[3], s1);
    return s0 + s1;
}

// full-row score: two 16B fragments per side (low half + high half of 256B row)
__device__ __forceinline__ float score2(u32x4 a0, u32x4 a1, u32x4 b0, u32x4 b1) {
    return dot8h(a0, b0) + dot8h(a1, b1);
}

// forced vector load: SGPR base + 32-bit per-lane voffset (+imm). asm volatile
// cannot be sunk/split by the scheduler or register allocator.
#define GLD_LO(dst, base, voff) \
    asm volatile("global_load_dwordx4 %0, %1, %2" \
                 : "=v"(dst) : "v"(voff), "s"(base))
#define GLD_HI(dst, base, voff) \
    asm volatile("global_load_dwordx4 %0, %1, %2 offset:128" \
                 : "=v"(dst) : "v"(voff), "s"(base))

__global__ void ns_init_kernel(float* acc) {
    acc[0] = 0.0f;
    acc[1] = 0.0f;
}

// ---- streaming fp32 -> fp16 conversion of both tables ----
__global__ __launch_bounds__(256) void ns_convert_kernel(
    const float* __restrict__ iemb, const float* __restrict__ oemb,
    f16* __restrict__ iembH, f16* __restrict__ oembH)
{
    const int n4 = VOCAB * DIM / 4;
    int i = blockIdx.x * blockDim.x + threadIdx.x;
    const int stride = gridDim.x * blockDim.x;
    for (; i < n4; i += stride) {
        float4 a = reinterpret_cast<const float4*>(iemb)[i];
        f16x4 ha = {(f16)a.x, (f16)a.y, (f16)a.z, (f16)a.w};
        reinterpret_cast<f16x4*>(iembH)[i] = ha;
        float4 b = reinterpret_cast<const float4*>(oemb)[i];
        f16x4 hb = {(f16)b.x, (f16)b.y, (f16)b.z, (f16)b.w};
        reinterpret_cast<f16x4*>(oembH)[i] = hb;
    }
}

// ---- fp16 gather loss: 8 lanes/element, 2 elements per batch, 28 inline-asm
// loads kept in flight per wave (dataflow-forced: 112 dest VGPRs live across
// the vmcnt drain). launch_bounds(256,3): 168-VGPR budget.
__global__ __launch_bounds__(NTHREADS, 3) void ns_loss_h_kernel(
    const int* __restrict__ tgt,
    const int* __restrict__ ctx,
    const int* __restrict__ negw,
    const f16* __restrict__ iembH,
    const f16* __restrict__ oembH,
    float* __restrict__ acc)
{
    const int tid = threadIdx.x;
    const uint32_t lo = (uint32_t)((tid & 7) << 4);            // 16B chunk in low half-row
    const int g = (blockIdx.x * NTHREADS + tid) >> 3;          // global 8-lane group id

    float pos = 0.0f, neg = 0.0f;

    #pragma unroll
    for (int m = 0; m < EPG8 / 2; ++m) {
        const int e0 = g + (2 * m + 0) * NGRP8;
        const int e1 = g + (2 * m + 1) * NGRP8;

        // ---- index loads (normal; compiler drains these before voff calc) ----
        const int* nb0 = negw + (size_t)e0 * NEG;
        const int* nb1 = negw + (size_t)e1 * NEG;
        const uint32_t vt0 = ((uint32_t)tgt[e0] << 8) + lo;
        const uint32_t vc0 = ((uint32_t)ctx[e0] << 8) + lo;
        const uint32_t v00 = ((uint32_t)nb0[0] << 8) + lo;
        const uint32_t v01 = ((uint32_t)nb0[1] << 8) + lo;
        const uint32_t v02 = ((uint32_t)nb0[2] << 8) + lo;
        const uint32_t v03 = ((uint32_t)nb0[3] << 8) + lo;
        const uint32_t v04 = ((uint32_t)nb0[4] << 8) + lo;
        const uint32_t vt1 = ((uint32_t)tgt[e1] << 8) + lo;
        const uint32_t vc1 = ((uint32_t)ctx[e1] << 8) + lo;
        const uint32_t v10 = ((uint32_t)nb1[0] << 8) + lo;
        const uint32_t v11 = ((uint32_t)nb1[1] << 8) + lo;
        const uint32_t v12 = ((uint32_t)nb1[2] << 8) + lo;
        const uint32_t v13 = ((uint32_t)nb1[3] << 8) + lo;
        const uint32_t v14 = ((uint32_t)nb1[4] << 8) + lo;

        // ---- 28 forced loads, all issued before any wait ----
        u32x4 t0a, t0b, c0a, c0b, a0a, a0b, a1a, a1b, a2a, a2b, a3a, a3b, a4a, a4b;
        u32x4 t1a, t1b, c1a, c1b, b0a, b0b, b1a, b1b, b2a, b2b, b3a, b3b, b4a, b4b;

        GLD_LO(t0a, iembH, vt0);  GLD_HI(t0b, iembH, vt0);
        GLD_LO(c0a, oembH, vc0);  GLD_HI(c0b, oembH, vc0);
        GLD_LO(a0a, oembH, v00);  GLD_HI(a0b, oembH, v00);
        GLD_LO(a1a, oembH, v01);  GLD_HI(a1b, oembH, v01);
        GLD_LO(a2a, oembH, v02);  GLD_HI(a2b, oembH, v02);
        GLD_LO(a3a, oembH, v03);  GLD_HI(a3b, oembH, v03);
        GLD_LO(a4a, oembH, v04);  GLD_HI(a4b, oembH, v04);
        GLD_LO(t1a, iembH, vt1);  GLD_HI(t1b, iembH, vt1);
        GLD_LO(c1a, oembH, vc1);  GLD_HI(c1b, oembH, vc1);
        GLD_LO(b0a, oembH, v10);  GLD_HI(b0b, oembH, v10);
        GLD_LO(b1a, oembH, v11);  GLD_HI(b1b, oembH, v11);
        GLD_LO(b2a, oembH, v12);  GLD_HI(b2b, oembH, v12);
        GLD_LO(b3a, oembH, v13);  GLD_HI(b3b, oembH, v13);
        GLD_LO(b4a, oembH, v14);  GLD_HI(b4b, oembH, v14);

        asm volatile("s_waitcnt vmcnt(0)" ::: "memory");
        __builtin_amdgcn_sched_barrier(0);

        // ---- compute both elements ----
        float dp0 = score2(t0a, t0b, c0a, c0b);
        float d00 = score2(t0a, t0b, a0a, a0b);
        float d01 = score2(t0a, t0b, a1a, a1b);
        float d02 = score2(t0a, t0b, a2a, a2b);
        float d03 = score2(t0a, t0b, a3a, a3b);
        float d04 = score2(t0a, t0b, a4a, a4b);
        float dp1 = score2(t1a, t1b, c1a, c1b);
        float d10 = score2(t1a, t1b, b0a, b0b);
        float d11 = score2(t1a, t1b, b1a, b1b);
        float d12 = score2(t1a, t1b, b2a, b2b);
        float d13 = score2(t1a, t1b, b3a, b3b);
        float d14 = score2(t1a, t1b, b4a, b4b);

        // butterfly over the 8-lane group
        #pragma unroll
        for (int s = 4; s >= 1; s >>= 1) {
            dp0 += __shfl_xor(dp0, s, 64);
            d00 += __shfl_xor(d00, s, 64);
            d01 += __shfl_xor(d01, s, 64);
            d02 += __shfl_xor(d02, s, 64);
            d03 += __shfl_xor(d03, s, 64);
            d04 += __shfl_xor(d04, s, 64);
            dp1 += __shfl_xor(dp1, s, 64);
            d10 += __shfl_xor(d10, s, 64);
            d11 += __shfl_xor(d11, s, 64);
            d12 += __shfl_xor(d12, s, 64);
            d13 += __shfl_xor(d13, s, 64);
            d14 += __shfl_xor(d14, s, 64);
        }

        // all 8 lanes accumulate (8x redundancy divided out in finalize)
        pos += softplus_fast(-dp0) + softplus_fast(-dp1);
        neg += softplus_fast(d00) + softplus_fast(d01) + softplus_fast(d02)
             + softplus_fast(d03) + softplus_fast(d04)
             + softplus_fast(d10) + softplus_fast(d11) + softplus_fast(d12)
             + softplus_fast(d13) + softplus_fast(d14);
    }

    // full-wave butterfly, one atomic pair per wave
    #pragma unroll
    for (int s = 32; s >= 1; s >>= 1) {
        pos += __shfl_xor(pos, s, 64);
        neg += __shfl_xor(neg, s, 64);
    }
    if ((tid & 63) == 0) {
        atomicAdd(&acc[0], pos);
        atomicAdd(&acc[1], neg);
    }
}

__global__ void ns_finalize_h_kernel(const float* __restrict__ acc, float* __restrict__ out) {
    // each element accumulated by its 8 lanes
    out[0] = acc[0] * (1.0f / ((float)BATCH * 8.0f));
    out[1] = acc[1] * (1.0f / ((float)BATCH * (float)NEG * 8.0f));
}

// ================= fp32 fallback (round-4 kernel, unchanged) =================
__device__ __forceinline__ float dot4f(float4 a, float4 b) {
    return a.x * b.x + a.y * b.y + a.z * b.z + a.w * b.w;
}

__global__ __launch_bounds__(256) void ns_loss_f32_kernel(
    const int* __restrict__ tgt, const int* __restrict__ ctx,
    const int* __restrict__ negw,
    const float* __restrict__ iemb, const float* __restrict__ oemb,
    float* __restrict__ acc)
{
    const int tid = threadIdx.x;
    const int r   = tid & 7;
    const int grp = tid >> 3;
    const int e0  = blockIdx.x * 32 + grp;
    const int estride = gridDim.x * 32;

    float pos_acc = 0.0f, neg_acc = 0.0f;
    for (int e = e0; e < BATCH; e += estride) {
        const int tw = tgt[e];
        const int cw = ctx[e];
        const float4* tp = reinterpret_cast<const float4*>(iemb + (size_t)tw * DIM) + r * 4;
        const float4 t0 = tp[0], t1 = tp[1], t2 = tp[2], t3 = tp[3];
        const float4* cp = reinterpret_cast<const float4*>(oemb + (size_t)cw * DIM) + r * 4;
        float dp = dot4f(t0, cp[0]) + dot4f(t1, cp[1]) + dot4f(t2, cp[2]) + dot4f(t3, cp[3]);
        float dn[NEG];
        #pragma unroll
        for (int j = 0; j < NEG; ++j) {
            const int nw = negw[e * NEG + j];
            const float4* np_ = reinterpret_cast<const float4*>(oemb + (size_t)nw * DIM) + r * 4;
            dn[j] = dot4f(t0, np_[0]) + dot4f(t1, np_[1]) + dot4f(t2, np_[2]) + dot4f(t3, np_[3]);
        }
        #pragma unroll
        for (int m = 4; m >= 1; m >>= 1) {
            dp += __shfl_xor(dp, m, 64);
            #pragma unroll
            for (int j = 0; j < NEG; ++j) dn[j] += __shfl_xor(dn[j], m, 64);
        }
        pos_acc += softplus_fast(-dp);
        float s = 0.0f;
        #pragma unroll
        for (int j = 0; j < NEG; ++j) s += softplus_fast(dn[j]);
        neg_acc += s;
    }
    #pragma unroll
    for (int m = 32; m >= 1; m >>= 1) {
        pos_acc += __shfl_xor(pos_acc, m, 64);
        neg_acc += __shfl_xor(neg_acc, m, 64);
    }
    if ((tid & 63) == 0) {
        atomicAdd(&acc[0], pos_acc);
        atomicAdd(&acc[1], neg_acc);
    }
}

__global__ void ns_finalize_f32_kernel(const float* __restrict__ acc, float* __restrict__ out) {
    out[0] = acc[0] * (1.0f / ((float)BATCH * 8.0f));
    out[1] = acc[1] * (1.0f / ((float)BATCH * (float)NEG * 8.0f));
}

extern "C" void kernel_launch(void* const* d_in, const int* in_sizes, int n_in,
                              void* d_out, int out_size, void* d_ws, size_t ws_size,
                              hipStream_t stream) {
    const int*   tgt  = (const int*)d_in[0];
    const int*   ctx  = (const int*)d_in[1];
    const int*   negw = (const int*)d_in[2];
    const float* iemb = (const float*)d_in[3];
    const float* oemb = (const float*)d_in[4];
    float* out = (float*)d_out;
    float* acc = (float*)d_ws;

    if (ws_size >= WS_NEEDED) {
        f16* iembH = (f16*)((char*)d_ws + 256);
        f16* oembH = (f16*)((char*)d_ws + 256 + TABLE_HALF_BYTES);
        ns_init_kernel<<<1, 1, 0, stream>>>(acc);
        ns_convert_kernel<<<2048, 256, 0, stream>>>(iemb, oemb, iembH, oembH);
        ns_loss_h_kernel<<<NBLOCK, NTHREADS, 0, stream>>>(tgt, ctx, negw, iembH, oembH, acc);
        ns_finalize_h_kernel<<<1, 1, 0, stream>>>(acc, out);
    } else {
        ns_init_kernel<<<1, 1, 0, stream>>>(acc);
        ns_loss_f32_kernel<<<2048, 256, 0, stream>>>(tgt, ctx, negw, iemb, oemb, acc);
        ns_finalize_f32_kernel<<<1, 1, 0, stream>>>(acc, out);
    }
}